// Round 2
// baseline (29.619 us; speedup 1.0000x reference)
//
#include <hip/hip_runtime.h>
#include <math.h>

// STP forward as affine recurrence on r = imu/mu:
//   d[n] = a + (x[n-1]+x[n])/2
//   r[n] = exp(-d[n]) * (r[n-1] + x[n-1]/2) + x[n]/2
// td[n] = (r[n] > 0) ? 1 - r[n] : 1 ; chunk(500)-boundary carry clamp r>0?r:1.
// Carry influence decays by exp(-500a) <= 1.4e-11 across a chunk, so each
// chunk's raw end value is computed carry-free from composed segment (A,B).
//
// k1: one thread per 50 steps, TWO interleaved independent 25-step affine
//     chains (ILP). exp(-d) = exp(-a)*exp(-xp/2)*exp(-x/2): one deg-12
//     Taylor poly (|arg|<=0.45, err<5e-15) per step, exp(-x/2) reused as
//     next step's exp(-xp/2). Writes 20 (A,B) pairs per chunk.
// k2: one thread per 25 steps (256k threads), composes its entry state in
//     f64 from the AB table, then replays in f32 with __expf.

#define TDIM 50000
#define UDIM 16
#define NCH 100     // chunks (T/500)
#define SEG2 20     // 25-step sub-segments per chunk
#define NSEQ 128    // B*U

struct alignas(16) AB { double A; double B; };

__device__ __forceinline__ float clean(float v) { return (v != v) ? 0.0f : v; }

// exp(y) for |y| <= ~0.5, deg-12 Taylor Horner. Truncation < 5e-15 rel.
__device__ __forceinline__ double exp_small(double y) {
    double p = 2.08767569878681e-9;          // 1/12!
    p = fma(p, y, 2.505210838544172e-8);     // 1/11!
    p = fma(p, y, 2.755731922398589e-7);     // 1/10!
    p = fma(p, y, 2.7557319223985893e-6);    // 1/9!
    p = fma(p, y, 2.48015873015873e-5);      // 1/8!
    p = fma(p, y, 1.984126984126984e-4);     // 1/7!
    p = fma(p, y, 1.3888888888888889e-3);    // 1/6!
    p = fma(p, y, 8.333333333333333e-3);     // 1/5!
    p = fma(p, y, 4.1666666666666664e-2);    // 1/4!
    p = fma(p, y, 1.6666666666666666e-1);    // 1/3!
    p = fma(p, y, 0.5);                      // 1/2!
    p = fma(p, y, 1.0);
    p = fma(p, y, 1.0);
    return p;
}

__global__ __launch_bounds__(64) void stp_k1(
    const float* __restrict__ inp, const float* __restrict__ uu,
    const float* __restrict__ tauv, AB* __restrict__ ab)
{
    const int tid = blockIdx.x * 64 + threadIdx.x;   // 0..127999
    const int sbu = tid & (NSEQ - 1);
    const int seg = tid >> 7;                        // 50-step segment 0..999
    const int u   = sbu & (UDIM - 1);
    const int b   = sbu >> 4;
    const int n0  = seg * 50;

    // Replicate reference f32 -> f64 promotion exactly:
    const float ui   = (fabsf(uu[u]) / 100.0f) * 100.0f;
    const float taui = fmaxf(fabsf(tauv[u]), 0.02001f) * 100.0f;
    const double a   = (double)(1.0f / taui);
    const double ea  = exp(-a);                      // loop-invariant, libm

    const float* p = inp + ((size_t)b * TDIM + n0) * UDIM + u;

    // chain 1: steps [0,25), chain 2: steps [25,50)
    double xp1 = (n0 != 0) ? (double)(ui * clean(p[-UDIM])) : 0.0;
    double xp2 = (double)(ui * clean(p[24 * UDIM]));
    double ep1 = exp_small(-0.5 * xp1);              // exp(-xp/2) carried
    double ep2 = exp_small(-0.5 * xp2);
    double A1 = 1.0, B1 = 0.0, A2 = 1.0, B2 = 0.0;

#pragma unroll 5
    for (int t = 0; t < 25; ++t) {
        const double x1 = (double)(ui * clean(p[(size_t)t * UDIM]));
        const double x2 = (double)(ui * clean(p[(size_t)(t + 25) * UDIM]));
        const double ex1 = exp_small(-0.5 * x1);
        const double ex2 = exp_small(-0.5 * x2);
        const double e1 = ea * ep1 * ex1;            // exp(-(a+(xp+x)/2))
        const double e2 = ea * ep2 * ex2;
        A1 *= e1;  B1 = fma(e1, fma(xp1, 0.5, B1), 0.5 * x1);
        A2 *= e2;  B2 = fma(e2, fma(xp2, 0.5, B2), 0.5 * x2);
        ep1 = ex1; ep2 = ex2; xp1 = x1; xp2 = x2;
    }
    // sub-segment indices: global 25-step seg = 2*seg, 2*seg+1
    ab[(size_t)(2 * seg) * NSEQ + sbu]     = {A1, B1};
    ab[(size_t)(2 * seg + 1) * NSEQ + sbu] = {A2, B2};
}

__global__ __launch_bounds__(64) void stp_k2(
    const float* __restrict__ inp, const float* __restrict__ uu,
    const float* __restrict__ tauv, const AB* __restrict__ ab,
    float* __restrict__ out)
{
    const int tid = blockIdx.x * 64 + threadIdx.x;   // 0..255999
    const int sbu = tid & (NSEQ - 1);
    const int seg = tid >> 7;                        // 25-step segment 0..1999
    const int c   = seg / SEG2;
    const int s   = seg - c * SEG2;
    const int u   = sbu & (UDIM - 1);
    const int b   = sbu >> 4;
    const int n0  = seg * 25;

    const float ui   = (fabsf(uu[u]) / 100.0f) * 100.0f;
    const float taui = fmaxf(fabsf(tauv[u]), 0.02001f) * 100.0f;
    const float af   = 1.0f / taui;

    double r_in = 0.0;      // chunk 0 entry: imu0 = 0
    double td_prev = 1.0;   // out[0] uses pad value 1.0
    if (c > 0) {
        // raw end of previous chunk, carry-free (decay <= 1.4e-11)
        const AB* q = ab + (size_t)(c - 1) * SEG2 * NSEQ + sbu;
        double r = 0.0;
        #pragma unroll
        for (int j = 0; j < SEG2; ++j) {
            const AB e = q[(size_t)j * NSEQ];
            r = fma(e.A, r, e.B);
        }
        r_in    = (r > 0.0) ? r : 1.0;               // clamped carry
        td_prev = (r > 0.0) ? 1.0 - r : 1.0;         // td from RAW end value
    }
    if (s > 0) {
        const AB* q = ab + (size_t)c * SEG2 * NSEQ + sbu;
        for (int j = 0; j < s; ++j) {
            const AB e = q[(size_t)j * NSEQ];
            r_in = fma(e.A, r_in, e.B);
        }
        td_prev = (r_in > 0.0) ? 1.0 - r_in : 1.0;
    }

    const float* p = inp + ((size_t)b * TDIM + n0) * UDIM + u;
    float*       o = out + ((size_t)b * TDIM + n0) * UDIM + u;
    float xp = (n0 != 0) ? ui * clean(p[-UDIM]) : 0.0f;

    float r   = (float)r_in;
    float tdp = (float)td_prev;
#pragma unroll 5
    for (int t = 0; t < 25; ++t) {
        const float ts = clean(p[(size_t)t * UDIM]);
        const float x  = ui * ts;
        const float d  = af + (xp + x) * 0.5f;
        const float e  = __expf(-d);
        r = e * (r + xp * 0.5f) + x * 0.5f;
        o[(size_t)t * UDIM] = ts * tdp;              // out[n] = tstim[n]*td[n-1]
        tdp = (r > 0.0f) ? 1.0f - r : 1.0f;
        xp = x;
    }
}

extern "C" void kernel_launch(void* const* d_in, const int* in_sizes, int n_in,
                              void* d_out, int out_size, void* d_ws, size_t ws_size,
                              hipStream_t stream) {
    const float* inp  = (const float*)d_in[0];
    const float* uu   = (const float*)d_in[1];
    const float* tauv = (const float*)d_in[2];
    float* out = (float*)d_out;
    AB* ab = (AB*)d_ws;  // 256,000 * 16 B = 4,096,000 B of scratch

    stp_k1<<<dim3(2000), dim3(64), 0, stream>>>(inp, uu, tauv, ab);
    stp_k2<<<dim3(4000), dim3(64), 0, stream>>>(inp, uu, tauv, ab, out);
}

// Round 3
// 25.913 us; speedup vs baseline: 1.1430x; 1.1430x over previous
//
#include <hip/hip_runtime.h>
#include <math.h>

// STP forward as affine recurrence on r = imu/mu:
//   d[n] = a + (x[n-1]+x[n])/2
//   r[n] = exp(-d[n]) * (r[n-1] + x[n-1]/2) + x[n]/2
// td[n] = (r[n] > 0) ? 1 - r[n] : 1 ; chunk(500)-boundary carry clamp r>0?r:1.
// Carry influence decays by exp(-500a) <= ~2e-9 across a chunk, so each
// chunk's raw end is computed carry-free from its own 20 segment (A,B)s.
//
// kA: block = (chunk c, batch b), 320 thr = 20 segs x 16 u. Each thread:
//     25-step affine (A,B) via factored exp (one deg-12 Taylor per step),
//     LDS prefix scan -> (P,Q), store PQ per seg + raw chunk end r_raw.
// kB: one thread per (seg, sbu): r_in = P*clamp(r_raw[c-1]) + Q (2 fma),
//     then 25-step f32 replay with __expf. Pure streaming.

#define TDIM 50000
#define UDIM 16
#define NCH 100
#define SEG 20      // 25-step sub-segments per chunk
#define SLEN 25
#define NSEQ 128    // B*U

struct alignas(16) PQt { double P; double Q; };

__device__ __forceinline__ float clean(float v) { return (v != v) ? 0.0f : v; }

// exp(y) for |y| <= ~0.7, deg-12 Taylor Horner. rel err < ~2e-12.
__device__ __forceinline__ double exp_small(double y) {
    double p = 2.08767569878681e-9;          // 1/12!
    p = fma(p, y, 2.505210838544172e-8);     // 1/11!
    p = fma(p, y, 2.755731922398589e-7);     // 1/10!
    p = fma(p, y, 2.7557319223985893e-6);    // 1/9!
    p = fma(p, y, 2.48015873015873e-5);      // 1/8!
    p = fma(p, y, 1.984126984126984e-4);     // 1/7!
    p = fma(p, y, 1.3888888888888889e-3);    // 1/6!
    p = fma(p, y, 8.333333333333333e-3);     // 1/5!
    p = fma(p, y, 4.1666666666666664e-2);    // 1/4!
    p = fma(p, y, 1.6666666666666666e-1);    // 1/3!
    p = fma(p, y, 0.5);                      // 1/2!
    p = fma(p, y, 1.0);
    p = fma(p, y, 1.0);
    return p;
}

__global__ __launch_bounds__(320, 4) void stp_kA(
    const float* __restrict__ inp, const float* __restrict__ uu,
    const float* __restrict__ tauv, PQt* __restrict__ PQ,
    double* __restrict__ rraw)
{
    const int c = blockIdx.x >> 3;           // chunk 0..99
    const int b = blockIdx.x & 7;            // batch 0..7
    const int s = threadIdx.x >> 4;          // seg-in-chunk 0..19
    const int u = threadIdx.x & 15;
    const int n0 = c * 500 + s * SLEN;

    // Replicate reference f32 -> f64 promotion exactly:
    const float ui   = (fabsf(uu[u]) / 100.0f) * 100.0f;
    const float taui = fmaxf(fabsf(tauv[u]), 0.02001f) * 100.0f;
    const double a   = (double)(1.0f / taui);
    const double ea  = exp(-a);              // loop-invariant, libm

    const float* p = inp + ((size_t)b * TDIM + n0) * UDIM + u;
    double xp = (n0 != 0) ? (double)(ui * clean(p[-UDIM])) : 0.0;
    double ep = exp_small(-0.5 * xp);        // exp(-xp/2), carried step-to-step
    double A = 1.0, B = 0.0;

#pragma unroll 5
    for (int t = 0; t < SLEN; ++t) {
        const double x  = (double)(ui * clean(p[(size_t)t * UDIM]));
        const double ex = exp_small(-0.5 * x);
        const double e  = ea * ep * ex;      // exp(-(a + (xp+x)/2))
        A *= e;
        B = fma(e, fma(xp, 0.5, B), 0.5 * x);
        ep = ex; xp = x;
    }

    __shared__ double sA[SEG][16];
    __shared__ double sB[SEG][16];
    sA[s][u] = A;
    sB[s][u] = B;
    __syncthreads();

    // prefix over segs 0..s-1 (left-to-right): r -> P*r + Q
    double P = 1.0, Q = 0.0;
    for (int j = 0; j < s; ++j) {
        const double Aj = sA[j][u];
        const double Bj = sB[j][u];
        P *= Aj;
        Q = fma(Aj, Q, Bj);
    }

    const int sbu = b * 16 + u;
    PQ[((size_t)c * SEG + s) * NSEQ + sbu] = {P, Q};
    if (s == SEG - 1) {
        // raw chunk end from r_in = 0: own segment applied to prefix value Q
        rraw[(size_t)c * NSEQ + sbu] = fma(A, Q, B);
    }
}

__global__ __launch_bounds__(128, 4) void stp_kB(
    const float* __restrict__ inp, const float* __restrict__ uu,
    const float* __restrict__ tauv, const PQt* __restrict__ PQ,
    const double* __restrict__ rraw, float* __restrict__ out)
{
    const int tid = blockIdx.x * 128 + threadIdx.x;
    const int sbu = tid & (NSEQ - 1);
    const int seg = tid >> 7;                // global 25-seg 0..1999
    const int c   = seg / SEG;
    const int s   = seg - c * SEG;
    const int u   = sbu & 15;
    const int b   = sbu >> 4;
    const int n0  = seg * SLEN;

    const float ui   = (fabsf(uu[u]) / 100.0f) * 100.0f;
    const float taui = fmaxf(fabsf(tauv[u]), 0.02001f) * 100.0f;
    const float af   = 1.0f / taui;

    const PQt pq = PQ[(size_t)seg * NSEQ + sbu];
    double carry = 0.0, tdp_d = 1.0;         // chunk 0: imu0=0; out[0] pad=1
    if (c > 0) {
        const double re = rraw[(size_t)(c - 1) * NSEQ + sbu];
        carry = (re > 0.0) ? re : 1.0;       // clamped carry
        tdp_d = (re > 0.0) ? 1.0 - re : 1.0; // td from RAW end of prev chunk
    }
    const double r_in = fma(pq.P, carry, pq.Q);
    if (s > 0) tdp_d = (r_in > 0.0) ? 1.0 - r_in : 1.0;

    const float* p = inp + ((size_t)b * TDIM + n0) * UDIM + u;
    float*       o = out + ((size_t)b * TDIM + n0) * UDIM + u;
    float xp = (n0 != 0) ? ui * clean(p[-UDIM]) : 0.0f;

    float r   = (float)r_in;
    float tdp = (float)tdp_d;
#pragma unroll 5
    for (int t = 0; t < SLEN; ++t) {
        const float ts = clean(p[(size_t)t * UDIM]);
        const float x  = ui * ts;
        const float d  = af + (xp + x) * 0.5f;
        const float e  = __expf(-d);
        r = e * (r + xp * 0.5f) + x * 0.5f;
        o[(size_t)t * UDIM] = ts * tdp;      // out[n] = tstim[n]*td[n-1]
        tdp = (r > 0.0f) ? 1.0f - r : 1.0f;
        xp = x;
    }
}

extern "C" void kernel_launch(void* const* d_in, const int* in_sizes, int n_in,
                              void* d_out, int out_size, void* d_ws, size_t ws_size,
                              hipStream_t stream) {
    const float* inp  = (const float*)d_in[0];
    const float* uu   = (const float*)d_in[1];
    const float* tauv = (const float*)d_in[2];
    float* out = (float*)d_out;

    PQt*    PQ   = (PQt*)d_ws;                          // 4,096,000 B
    double* rraw = (double*)((char*)d_ws + 4096000);    // 102,400 B

    stp_kA<<<dim3(NCH * 8), dim3(320), 0, stream>>>(inp, uu, tauv, PQ, rraw);
    stp_kB<<<dim3(2000), dim3(128), 0, stream>>>(inp, uu, tauv, PQ, rraw, out);
}